// Round 1
// baseline (1172.725 us; speedup 1.0000x reference)
//
#include <hip/hip_runtime.h>
#include <cstdint>
#include <cstddef>

// GIN 3-layer + BN + mean-pool, fp32 baseline.
// ws layout: A(51.2MB) B(51.2MB) rowptr deg cursor col bsum stats  => ~101.3 MB total.

constexpr int N_NODES  = 50000;
constexpr int N_EDGES  = 800000;
constexpr int F_IN     = 128;
constexpr int HID      = 256;
constexpr int N_GRAPHS = 512;
constexpr float BN_EPS = 1e-5f;

constexpr int SCAN_CHUNK = 4096;
constexpr int SCAN_NB    = (N_NODES + SCAN_CHUNK - 1) / SCAN_CHUNK; // 13

// ---------------- CSR build ----------------
__global__ void hist_k(const int* __restrict__ dst, int* __restrict__ deg) {
    int e = blockIdx.x * 256 + threadIdx.x;
    if (e < N_EDGES) atomicAdd(&deg[dst[e]], 1);
}

__global__ void scan_part1(const int* __restrict__ in, int* __restrict__ bsum) {
    __shared__ int sm[256];
    int t = threadIdx.x;
    int base = blockIdx.x * SCAN_CHUNK + t * 16;
    int s = 0;
#pragma unroll
    for (int j = 0; j < 16; j++) { int idx = base + j; s += (idx < N_NODES) ? in[idx] : 0; }
    sm[t] = s; __syncthreads();
    for (int off = 128; off > 0; off >>= 1) {
        if (t < off) sm[t] += sm[t + off];
        __syncthreads();
    }
    if (t == 0) bsum[blockIdx.x] = sm[0];
}

__global__ void scan_tops(int* __restrict__ bsum, int* __restrict__ rowptr) {
    if (threadIdx.x == 0 && blockIdx.x == 0) {
        int acc = 0;
        for (int i = 0; i < SCAN_NB; i++) { int v = bsum[i]; bsum[i] = acc; acc += v; }
        rowptr[N_NODES] = acc; // == N_EDGES
    }
}

__global__ void scan_final(const int* __restrict__ in, const int* __restrict__ bsum,
                           int* __restrict__ rowptr, int* __restrict__ cursor) {
    __shared__ int sm[256];
    int t = threadIdx.x;
    int base = blockIdx.x * SCAN_CHUNK + t * 16;
    int loc[16]; int s = 0;
#pragma unroll
    for (int j = 0; j < 16; j++) { int idx = base + j; loc[j] = s; s += (idx < N_NODES) ? in[idx] : 0; }
    sm[t] = s; __syncthreads();
    for (int off = 1; off < 256; off <<= 1) {
        int v = (t >= off) ? sm[t - off] : 0;
        __syncthreads();
        sm[t] += v;
        __syncthreads();
    }
    int excl = sm[t] - s + bsum[blockIdx.x];
#pragma unroll
    for (int j = 0; j < 16; j++) {
        int idx = base + j;
        if (idx < N_NODES) { int rp = excl + loc[j]; rowptr[idx] = rp; cursor[idx] = rp; }
    }
}

__global__ void build_csr(const int* __restrict__ src, const int* __restrict__ dst,
                          int* __restrict__ cursor, int* __restrict__ col) {
    int e = blockIdx.x * 256 + threadIdx.x;
    if (e < N_EDGES) {
        int d = dst[e];
        int p = atomicAdd(&cursor[d], 1);
        col[p] = src[e];
    }
}

// ---------------- aggregation: out[n] = h[n] + sum_{e: dst=n} h[src[e]] ----------------
template <int F>
__global__ __launch_bounds__(256) void aggregate_k(const float* __restrict__ h,
                                                   const int* __restrict__ rowptr,
                                                   const int* __restrict__ col,
                                                   float* __restrict__ outp) {
    int node = blockIdx.x * 4 + (threadIdx.x >> 6);
    if (node >= N_NODES) return;
    int lane = threadIdx.x & 63;
    int beg = rowptr[node], end = rowptr[node + 1];
    if constexpr (F == 256) {
        const float4* hp = reinterpret_cast<const float4*>(h);
        float4 acc = hp[(size_t)node * 64 + lane];
        for (int e = beg; e < end; ++e) {
            int s = col[e];
            float4 v = hp[(size_t)s * 64 + lane];
            acc.x += v.x; acc.y += v.y; acc.z += v.z; acc.w += v.w;
        }
        reinterpret_cast<float4*>(outp)[(size_t)node * 64 + lane] = acc;
    } else { // F == 128
        const float2* hp = reinterpret_cast<const float2*>(h);
        float2 acc = hp[(size_t)node * 64 + lane];
        for (int e = beg; e < end; ++e) {
            int s = col[e];
            float2 v = hp[(size_t)s * 64 + lane];
            acc.x += v.x; acc.y += v.y;
        }
        reinterpret_cast<float2*>(outp)[(size_t)node * 64 + lane] = acc;
    }
}

// ---------------- GEMM: C[M][256] = relu(A[M][K] @ W[K][256] + bias) ----------------
// Block tile 64 rows x 256 cols; in-place safe (block reads only its own rows of A).
template <int K>
__global__ __launch_bounds__(256) void gemm_bias_relu(const float* __restrict__ A,
                                                      const float* __restrict__ W,
                                                      const float* __restrict__ bias,
                                                      float* __restrict__ C) {
    constexpr int KC = 32;
    __shared__ float As[KC][68];    // transposed: As[k][row], padded stride 68
    __shared__ float Ws[KC][260];   // Ws[k][col], padded stride 260
    const int r0 = blockIdx.x * 64;
    const int tid = threadIdx.x;
    const int tx = tid & 31;   // 0..31 -> cols tx*4 and 128+tx*4
    const int ty = tid >> 5;   // 0..7  -> rows ty*8..+7
    float acc[8][8] = {};

    for (int k0 = 0; k0 < K; k0 += KC) {
        { // A tile: 64 rows x 32 k
            int row = tid >> 2;          // 0..63
            int kc  = (tid & 3) * 8;     // 0,8,16,24
            float4 v0 = make_float4(0.f, 0.f, 0.f, 0.f), v1 = v0;
            if (r0 + row < N_NODES) {
                const float* ap = A + (size_t)(r0 + row) * K + k0 + kc;
                v0 = *reinterpret_cast<const float4*>(ap);
                v1 = *reinterpret_cast<const float4*>(ap + 4);
            }
            As[kc + 0][row] = v0.x; As[kc + 1][row] = v0.y;
            As[kc + 2][row] = v0.z; As[kc + 3][row] = v0.w;
            As[kc + 4][row] = v1.x; As[kc + 5][row] = v1.y;
            As[kc + 6][row] = v1.z; As[kc + 7][row] = v1.w;
        }
        { // W tile: 32 k x 256 cols
            int c   = (tid & 63) * 4;
            int kk0 = tid >> 6;          // 0..3
#pragma unroll
            for (int i = 0; i < 8; i++) {
                int kk = kk0 + i * 4;
                float4 v = *reinterpret_cast<const float4*>(&W[(size_t)(k0 + kk) * HID + c]);
                *reinterpret_cast<float4*>(&Ws[kk][c]) = v;
            }
        }
        __syncthreads();
#pragma unroll 4
        for (int kk = 0; kk < KC; ++kk) {
            float a[8], b[8];
            *reinterpret_cast<float4*>(&a[0]) = *reinterpret_cast<const float4*>(&As[kk][ty * 8]);
            *reinterpret_cast<float4*>(&a[4]) = *reinterpret_cast<const float4*>(&As[kk][ty * 8 + 4]);
            *reinterpret_cast<float4*>(&b[0]) = *reinterpret_cast<const float4*>(&Ws[kk][tx * 4]);
            *reinterpret_cast<float4*>(&b[4]) = *reinterpret_cast<const float4*>(&Ws[kk][128 + tx * 4]);
#pragma unroll
            for (int i = 0; i < 8; i++)
#pragma unroll
                for (int j = 0; j < 8; j++)
                    acc[i][j] += a[i] * b[j];
        }
        __syncthreads();
    }
    // epilogue: bias + relu + store
    float bl[8];
    *reinterpret_cast<float4*>(&bl[0]) = *reinterpret_cast<const float4*>(&bias[tx * 4]);
    *reinterpret_cast<float4*>(&bl[4]) = *reinterpret_cast<const float4*>(&bias[128 + tx * 4]);
#pragma unroll
    for (int i = 0; i < 8; i++) {
        int r = r0 + ty * 8 + i;
        if (r < N_NODES) {
            float4 o0, o1;
            o0.x = fmaxf(acc[i][0] + bl[0], 0.f);
            o0.y = fmaxf(acc[i][1] + bl[1], 0.f);
            o0.z = fmaxf(acc[i][2] + bl[2], 0.f);
            o0.w = fmaxf(acc[i][3] + bl[3], 0.f);
            o1.x = fmaxf(acc[i][4] + bl[4], 0.f);
            o1.y = fmaxf(acc[i][5] + bl[5], 0.f);
            o1.z = fmaxf(acc[i][6] + bl[6], 0.f);
            o1.w = fmaxf(acc[i][7] + bl[7], 0.f);
            *reinterpret_cast<float4*>(&C[(size_t)r * HID + tx * 4]) = o0;
            *reinterpret_cast<float4*>(&C[(size_t)r * HID + 128 + tx * 4]) = o1;
        }
    }
}

// ---------------- BatchNorm ----------------
__global__ void bn_stats(const float* __restrict__ z, float* __restrict__ stats) {
    int c = threadIdx.x;
    float s = 0.f, s2 = 0.f;
    for (int r = blockIdx.x; r < N_NODES; r += gridDim.x) {
        float v = z[(size_t)r * HID + c];
        s += v; s2 += v * v;
    }
    atomicAdd(&stats[c], s);
    atomicAdd(&stats[HID + c], s2);
}

__global__ void bn_finalize(const float* __restrict__ stats, const float* __restrict__ gamma,
                            const float* __restrict__ beta, float* __restrict__ sc) {
    int c = threadIdx.x;
    float mu  = stats[c] * (1.f / N_NODES);
    float var = stats[HID + c] * (1.f / N_NODES) - mu * mu;
    float g = gamma[c] * rsqrtf(var + BN_EPS);
    sc[c] = g;
    sc[HID + c] = beta[c] - mu * g;
}

__global__ void bn_apply(float* __restrict__ z, const float* __restrict__ sc) {
    int i = blockIdx.x * 256 + threadIdx.x; // float4 index, total N_NODES*64
    if (i >= N_NODES * 64) return;
    int c4 = (i & 63) * 4;
    float4 v = reinterpret_cast<float4*>(z)[i];
    v.x = v.x * sc[c4 + 0] + sc[HID + c4 + 0];
    v.y = v.y * sc[c4 + 1] + sc[HID + c4 + 1];
    v.z = v.z * sc[c4 + 2] + sc[HID + c4 + 2];
    v.w = v.w * sc[c4 + 3] + sc[HID + c4 + 3];
    reinterpret_cast<float4*>(z)[i] = v;
}

// ---------------- mean pool (batch sorted) ----------------
__device__ __forceinline__ int lowerb(const int* a, int key) {
    int lo = 0, hi = N_NODES;
    while (lo < hi) { int mid = (lo + hi) >> 1; if (a[mid] < key) lo = mid + 1; else hi = mid; }
    return lo;
}

__global__ void pool_k(const float* __restrict__ h, const int* __restrict__ batch,
                       float* __restrict__ out) {
    __shared__ int bnd[2];
    int g = blockIdx.x;
    if (threadIdx.x == 0) bnd[0] = lowerb(batch, g);
    if (threadIdx.x == 1) bnd[1] = lowerb(batch, g + 1);
    __syncthreads();
    int lo = bnd[0], hi = bnd[1];
    int c = threadIdx.x;
    float s = 0.f;
    for (int r = lo; r < hi; ++r) s += h[(size_t)r * HID + c];
    out[(size_t)g * HID + c] = s / fmaxf((float)(hi - lo), 1.f);
}

// ---------------- launch ----------------
extern "C" void kernel_launch(void* const* d_in, const int* in_sizes, int n_in,
                              void* d_out, int out_size, void* d_ws, size_t ws_size,
                              hipStream_t stream) {
    const float* x   = (const float*)d_in[0];
    const int*   ei  = (const int*)d_in[1];
    const int* batch = (const int*)d_in[2];
    const float* w1a = (const float*)d_in[3];
    const float* b1a = (const float*)d_in[4];
    const float* w2a = (const float*)d_in[5];
    const float* b2a = (const float*)d_in[6];
    const float* ga  = (const float*)d_in[7];
    const float* ba  = (const float*)d_in[8];
    const float* w1s = (const float*)d_in[9];
    const float* b1s = (const float*)d_in[10];
    const float* w2s = (const float*)d_in[11];
    const float* b2s = (const float*)d_in[12];
    const float* gs  = (const float*)d_in[13];
    const float* bs  = (const float*)d_in[14];
    const int* src = ei;
    const int* dst = ei + N_EDGES;

    char* ws = (char*)d_ws;
    size_t off = 0;
    auto alloc = [&](size_t bytes) { void* p = ws + off; off += (bytes + 255) & ~(size_t)255; return p; };
    float* A      = (float*)alloc(sizeof(float) * (size_t)N_NODES * HID);
    float* B      = (float*)alloc(sizeof(float) * (size_t)N_NODES * HID);
    int*   rowptr = (int*)alloc(sizeof(int) * (N_NODES + 1));
    int*   deg    = (int*)alloc(sizeof(int) * N_NODES);
    int*   cursor = (int*)alloc(sizeof(int) * N_NODES);
    int*   col    = (int*)alloc(sizeof(int) * N_EDGES);
    int*   bsum   = (int*)alloc(sizeof(int) * 64);
    float* stats  = (float*)alloc(sizeof(float) * 1024);
    float* out    = (float*)d_out;
    (void)ws_size; (void)in_sizes; (void)n_in; (void)out_size;

    // ---- CSR build (by dst) ----
    hipMemsetAsync(deg, 0, sizeof(int) * N_NODES, stream);
    hist_k<<<N_EDGES / 256, 256, 0, stream>>>(dst, deg);
    scan_part1<<<SCAN_NB, 256, 0, stream>>>(deg, bsum);
    scan_tops<<<1, 64, 0, stream>>>(bsum, rowptr);
    scan_final<<<SCAN_NB, 256, 0, stream>>>(deg, bsum, rowptr, cursor);
    build_csr<<<N_EDGES / 256, 256, 0, stream>>>(src, dst, cursor, col);

    const int AGG_GRID  = (N_NODES + 3) / 4;   // 12500
    const int GEMM_GRID = (N_NODES + 63) / 64; // 782
    const int BNAP_GRID = N_NODES * 64 / 256;  // 12500

    // ---- layer 1 (x: 128 feats) ----
    aggregate_k<128><<<AGG_GRID, 256, 0, stream>>>(x, rowptr, col, A);
    gemm_bias_relu<128><<<GEMM_GRID, 256, 0, stream>>>(A, w1a, b1a, B);
    gemm_bias_relu<256><<<GEMM_GRID, 256, 0, stream>>>(B, w2a, b2a, B);
    hipMemsetAsync(stats, 0, sizeof(float) * 512, stream);
    bn_stats<<<512, 256, 0, stream>>>(B, stats);
    bn_finalize<<<1, 256, 0, stream>>>(stats, ga, ba, stats + 512);
    bn_apply<<<BNAP_GRID, 256, 0, stream>>>(B, stats + 512);

    // ---- layer 2 ----
    aggregate_k<256><<<AGG_GRID, 256, 0, stream>>>(B, rowptr, col, A);
    gemm_bias_relu<256><<<GEMM_GRID, 256, 0, stream>>>(A, w1s, b1s, A);
    gemm_bias_relu<256><<<GEMM_GRID, 256, 0, stream>>>(A, w2s, b2s, A);
    hipMemsetAsync(stats, 0, sizeof(float) * 512, stream);
    bn_stats<<<512, 256, 0, stream>>>(A, stats);
    bn_finalize<<<1, 256, 0, stream>>>(stats, gs, bs, stats + 512);
    bn_apply<<<BNAP_GRID, 256, 0, stream>>>(A, stats + 512);

    // ---- layer 3 ----
    aggregate_k<256><<<AGG_GRID, 256, 0, stream>>>(A, rowptr, col, B);
    gemm_bias_relu<256><<<GEMM_GRID, 256, 0, stream>>>(B, w1s + 65536, b1s + 256, B);
    gemm_bias_relu<256><<<GEMM_GRID, 256, 0, stream>>>(B, w2s + 65536, b2s + 256, B);
    hipMemsetAsync(stats, 0, sizeof(float) * 512, stream);
    bn_stats<<<512, 256, 0, stream>>>(B, stats);
    bn_finalize<<<1, 256, 0, stream>>>(stats, gs + 256, bs + 256, stats + 512);
    bn_apply<<<BNAP_GRID, 256, 0, stream>>>(B, stats + 512);

    // ---- pool ----
    pool_k<<<N_GRAPHS, 256, 0, stream>>>(B, batch, out);
}

// Round 2
// 851.190 us; speedup vs baseline: 1.3777x; 1.3777x over previous
//
#include <hip/hip_runtime.h>
#include <cstdint>
#include <cstddef>

// GIN 3-layer + BN + mean-pool. R2: split-bf16 MFMA GEMM (fp32-grade accuracy).

constexpr int N_NODES  = 50000;
constexpr int N_EDGES  = 800000;
constexpr int F_IN     = 128;
constexpr int HID      = 256;
constexpr int N_GRAPHS = 512;
constexpr float BN_EPS = 1e-5f;

constexpr int SCAN_CHUNK = 4096;
constexpr int SCAN_NB    = (N_NODES + SCAN_CHUNK - 1) / SCAN_CHUNK; // 13

typedef unsigned short u16;
typedef u16 u16x8 __attribute__((ext_vector_type(8)));
typedef __bf16 bf16x8 __attribute__((ext_vector_type(8)));
typedef float f32x4 __attribute__((ext_vector_type(4)));

__device__ __forceinline__ u16 f2bf(float f) {
    uint32_t u = __float_as_uint(f);
    uint32_t r = (u + 0x7FFFu + ((u >> 16) & 1u)) >> 16;
    return (u16)r;
}
__device__ __forceinline__ float bf2f(u16 h) {
    return __uint_as_float(((uint32_t)h) << 16);
}

// ---------------- CSR build ----------------
__global__ void hist_k(const int* __restrict__ dst, int* __restrict__ deg) {
    int e = blockIdx.x * 256 + threadIdx.x;
    if (e < N_EDGES) atomicAdd(&deg[dst[e]], 1);
}

__global__ void scan_part1(const int* __restrict__ in, int* __restrict__ bsum) {
    __shared__ int sm[256];
    int t = threadIdx.x;
    int base = blockIdx.x * SCAN_CHUNK + t * 16;
    int s = 0;
#pragma unroll
    for (int j = 0; j < 16; j++) { int idx = base + j; s += (idx < N_NODES) ? in[idx] : 0; }
    sm[t] = s; __syncthreads();
    for (int off = 128; off > 0; off >>= 1) {
        if (t < off) sm[t] += sm[t + off];
        __syncthreads();
    }
    if (t == 0) bsum[blockIdx.x] = sm[0];
}

__global__ void scan_tops(int* __restrict__ bsum, int* __restrict__ rowptr) {
    if (threadIdx.x == 0 && blockIdx.x == 0) {
        int acc = 0;
        for (int i = 0; i < SCAN_NB; i++) { int v = bsum[i]; bsum[i] = acc; acc += v; }
        rowptr[N_NODES] = acc; // == N_EDGES
    }
}

__global__ void scan_final(const int* __restrict__ in, const int* __restrict__ bsum,
                           int* __restrict__ rowptr, int* __restrict__ cursor) {
    __shared__ int sm[256];
    int t = threadIdx.x;
    int base = blockIdx.x * SCAN_CHUNK + t * 16;
    int loc[16]; int s = 0;
#pragma unroll
    for (int j = 0; j < 16; j++) { int idx = base + j; loc[j] = s; s += (idx < N_NODES) ? in[idx] : 0; }
    sm[t] = s; __syncthreads();
    for (int off = 1; off < 256; off <<= 1) {
        int v = (t >= off) ? sm[t - off] : 0;
        __syncthreads();
        sm[t] += v;
        __syncthreads();
    }
    int excl = sm[t] - s + bsum[blockIdx.x];
#pragma unroll
    for (int j = 0; j < 16; j++) {
        int idx = base + j;
        if (idx < N_NODES) { int rp = excl + loc[j]; rowptr[idx] = rp; cursor[idx] = rp; }
    }
}

__global__ void build_csr(const int* __restrict__ src, const int* __restrict__ dst,
                          int* __restrict__ cursor, int* __restrict__ col) {
    int e = blockIdx.x * 256 + threadIdx.x;
    if (e < N_EDGES) {
        int d = dst[e];
        int p = atomicAdd(&cursor[d], 1);
        col[p] = src[e];
    }
}

// ---------------- aggregation: out[n] = h[n] + sum_{e: dst=n} h[src[e]] ----------------
template <int F>
__global__ __launch_bounds__(256) void aggregate_k(const float* __restrict__ h,
                                                   const int* __restrict__ rowptr,
                                                   const int* __restrict__ col,
                                                   float* __restrict__ outp) {
    int node = blockIdx.x * 4 + (threadIdx.x >> 6);
    if (node >= N_NODES) return;
    int lane = threadIdx.x & 63;
    int beg = rowptr[node], end = rowptr[node + 1];
    if constexpr (F == 256) {
        const float4* hp = reinterpret_cast<const float4*>(h);
        float4 acc = hp[(size_t)node * 64 + lane];
        for (int e = beg; e < end; ++e) {
            int s = col[e];
            float4 v = hp[(size_t)s * 64 + lane];
            acc.x += v.x; acc.y += v.y; acc.z += v.z; acc.w += v.w;
        }
        reinterpret_cast<float4*>(outp)[(size_t)node * 64 + lane] = acc;
    } else { // F == 128
        const float2* hp = reinterpret_cast<const float2*>(h);
        float2 acc = hp[(size_t)node * 64 + lane];
        for (int e = beg; e < end; ++e) {
            int s = col[e];
            float2 v = hp[(size_t)s * 64 + lane];
            acc.x += v.x; acc.y += v.y;
        }
        reinterpret_cast<float2*>(outp)[(size_t)node * 64 + lane] = acc;
    }
}

// ---------------- W pre-transpose + bf16 split: Wt[n][k] = hi/lo(W[k][n]) ----------------
__global__ void wsplit_k(const float* __restrict__ W, u16* __restrict__ th,
                         u16* __restrict__ tl, int K) {
    int idx = blockIdx.x * 256 + threadIdx.x; // total K*256
    int n = idx & 255, k = idx >> 8;
    float f = W[(size_t)k * 256 + n];
    u16 h = f2bf(f);
    th[(size_t)n * K + k] = h;
    tl[(size_t)n * K + k] = f2bf(f - bf2f(h));
}

// ---------------- split-bf16 MFMA GEMM: C[M][256] = relu(A[M][K] @ W + bias) ----------------
// Block: 128 rows x 256 cols (full N -> in-place safe). 4 waves, each 64x128.
// acc += Ahi*Whi + Alo*Whi + Ahi*Wlo  (lo*lo dropped, ~2^-18 rel err)
template <int K>
__global__ __launch_bounds__(256, 2) void gemm_mfma(const float* __restrict__ A,
                                                    const u16* __restrict__ Wth,
                                                    const u16* __restrict__ Wtl,
                                                    const float* __restrict__ bias,
                                                    float* __restrict__ C) {
    constexpr int BM = 128, BK = 32;
    __shared__ alignas(16) u16 Ah[BM * BK];
    __shared__ alignas(16) u16 Al[BM * BK];
    __shared__ alignas(16) u16 Bh[HID * BK];
    __shared__ alignas(16) u16 Bl[HID * BK];

    const int tid  = threadIdx.x;
    const int r0   = blockIdx.x * BM;
    const int lane = tid & 63, wid = tid >> 6;
    const int wm = wid >> 1, wn = wid & 1;
    const int l15 = lane & 15, kg = lane >> 4;

    const int arow = tid >> 1, ahalf = tid & 1;
    const bool avalid = (r0 + arow) < N_NODES;
    const float* aptr = A + (size_t)(r0 + arow) * K + ahalf * 16;
    const u16* bhptr = Wth + (size_t)tid * K;
    const u16* blptr = Wtl + (size_t)tid * K;

    f32x4 acc[4][8];
#pragma unroll
    for (int i = 0; i < 4; i++)
#pragma unroll
        for (int j = 0; j < 8; j++) acc[i][j] = (f32x4){0.f, 0.f, 0.f, 0.f};

    for (int k0 = 0; k0 < K; k0 += BK) {
        // ---- stage A tile (128 x 32 fp32 -> hi/lo bf16, chunk-swizzled) ----
        float av[16];
        if (avalid) {
#pragma unroll
            for (int j = 0; j < 4; j++)
                *reinterpret_cast<float4*>(&av[j * 4]) =
                    *reinterpret_cast<const float4*>(aptr + k0 + j * 4);
        } else {
#pragma unroll
            for (int i = 0; i < 16; i++) av[i] = 0.f;
        }
        u16x8 vh[2], vl[2];
#pragma unroll
        for (int j = 0; j < 2; j++)
#pragma unroll
            for (int i = 0; i < 8; i++) {
                float f = av[j * 8 + i];
                u16 h = f2bf(f);
                vh[j][i] = h;
                vl[j][i] = f2bf(f - bf2f(h));
            }
#pragma unroll
        for (int j = 0; j < 2; j++) {
            int c = ahalf * 2 + j;
            int off = arow * 64 + ((c ^ ((arow >> 1) & 3)) << 4);
            *reinterpret_cast<u16x8*>((char*)Ah + off) = vh[j];
            *reinterpret_cast<u16x8*>((char*)Al + off) = vl[j];
        }
        // ---- stage B tile (Wt[n][k] bf16, n = tid, chunk-swizzled) ----
#pragma unroll
        for (int j = 0; j < 4; j++) {
            u16x8 v = *reinterpret_cast<const u16x8*>(bhptr + k0 + j * 8);
            int off = tid * 64 + ((j ^ ((tid >> 1) & 3)) << 4);
            *reinterpret_cast<u16x8*>((char*)Bh + off) = v;
        }
#pragma unroll
        for (int j = 0; j < 4; j++) {
            u16x8 v = *reinterpret_cast<const u16x8*>(blptr + k0 + j * 8);
            int off = tid * 64 + ((j ^ ((tid >> 1) & 3)) << 4);
            *reinterpret_cast<u16x8*>((char*)Bl + off) = v;
        }
        __syncthreads();
        // ---- MFMA: wave tile 64x128, 96 mfma per K-step ----
        bf16x8 ah[4], al[4];
#pragma unroll
        for (int mi = 0; mi < 4; mi++) {
            int r = wm * 64 + mi * 16 + l15;
            int off = r * 64 + ((kg ^ ((r >> 1) & 3)) << 4);
            ah[mi] = __builtin_bit_cast(bf16x8, *reinterpret_cast<const u16x8*>((const char*)Ah + off));
            al[mi] = __builtin_bit_cast(bf16x8, *reinterpret_cast<const u16x8*>((const char*)Al + off));
        }
#pragma unroll
        for (int ni = 0; ni < 8; ni++) {
            int n = wn * 128 + ni * 16 + l15;
            int off = n * 64 + ((kg ^ ((n >> 1) & 3)) << 4);
            bf16x8 bh = __builtin_bit_cast(bf16x8, *reinterpret_cast<const u16x8*>((const char*)Bh + off));
            bf16x8 bl = __builtin_bit_cast(bf16x8, *reinterpret_cast<const u16x8*>((const char*)Bl + off));
#pragma unroll
            for (int mi = 0; mi < 4; mi++) {
                acc[mi][ni] = __builtin_amdgcn_mfma_f32_16x16x32_bf16(ah[mi], bh, acc[mi][ni], 0, 0, 0);
                acc[mi][ni] = __builtin_amdgcn_mfma_f32_16x16x32_bf16(al[mi], bh, acc[mi][ni], 0, 0, 0);
                acc[mi][ni] = __builtin_amdgcn_mfma_f32_16x16x32_bf16(ah[mi], bl, acc[mi][ni], 0, 0, 0);
            }
        }
        __syncthreads();
    }
    // ---- epilogue: bias + relu + store (C/D layout: col=lane&15, row=(lane>>4)*4+rr) ----
    float bv[8];
#pragma unroll
    for (int ni = 0; ni < 8; ni++) bv[ni] = bias[wn * 128 + ni * 16 + l15];
#pragma unroll
    for (int mi = 0; mi < 4; mi++) {
        int rowb = r0 + wm * 64 + mi * 16 + kg * 4;
#pragma unroll
        for (int rr = 0; rr < 4; rr++) {
            int row = rowb + rr;
            if (row < N_NODES) {
                float* cp = C + (size_t)row * HID + wn * 128 + l15;
#pragma unroll
                for (int ni = 0; ni < 8; ni++)
                    cp[ni * 16] = fmaxf(acc[mi][ni][rr] + bv[ni], 0.f);
            }
        }
    }
}

// ---------------- BatchNorm ----------------
__global__ void bn_stats(const float* __restrict__ z, float* __restrict__ stats) {
    int c = threadIdx.x;
    float s = 0.f, s2 = 0.f;
    for (int r = blockIdx.x; r < N_NODES; r += gridDim.x) {
        float v = z[(size_t)r * HID + c];
        s += v; s2 += v * v;
    }
    atomicAdd(&stats[c], s);
    atomicAdd(&stats[HID + c], s2);
}

__global__ void bn_finalize(const float* __restrict__ stats, const float* __restrict__ gamma,
                            const float* __restrict__ beta, float* __restrict__ sc) {
    int c = threadIdx.x;
    float mu  = stats[c] * (1.f / N_NODES);
    float var = stats[HID + c] * (1.f / N_NODES) - mu * mu;
    float g = gamma[c] * rsqrtf(var + BN_EPS);
    sc[c] = g;
    sc[HID + c] = beta[c] - mu * g;
}

__global__ void bn_apply(float* __restrict__ z, const float* __restrict__ sc) {
    int i = blockIdx.x * 256 + threadIdx.x; // float4 index, total N_NODES*64
    if (i >= N_NODES * 64) return;
    int c4 = (i & 63) * 4;
    float4 v = reinterpret_cast<float4*>(z)[i];
    v.x = v.x * sc[c4 + 0] + sc[HID + c4 + 0];
    v.y = v.y * sc[c4 + 1] + sc[HID + c4 + 1];
    v.z = v.z * sc[c4 + 2] + sc[HID + c4 + 2];
    v.w = v.w * sc[c4 + 3] + sc[HID + c4 + 3];
    reinterpret_cast<float4*>(z)[i] = v;
}

// ---------------- mean pool (batch sorted) ----------------
__device__ __forceinline__ int lowerb(const int* a, int key) {
    int lo = 0, hi = N_NODES;
    while (lo < hi) { int mid = (lo + hi) >> 1; if (a[mid] < key) lo = mid + 1; else hi = mid; }
    return lo;
}

__global__ void pool_k(const float* __restrict__ h, const int* __restrict__ batch,
                       float* __restrict__ out) {
    __shared__ int bnd[2];
    int g = blockIdx.x;
    if (threadIdx.x == 0) bnd[0] = lowerb(batch, g);
    if (threadIdx.x == 1) bnd[1] = lowerb(batch, g + 1);
    __syncthreads();
    int lo = bnd[0], hi = bnd[1];
    int c = threadIdx.x;
    float s = 0.f;
    for (int r = lo; r < hi; ++r) s += h[(size_t)r * HID + c];
    out[(size_t)g * HID + c] = s / fmaxf((float)(hi - lo), 1.f);
}

// ---------------- launch ----------------
extern "C" void kernel_launch(void* const* d_in, const int* in_sizes, int n_in,
                              void* d_out, int out_size, void* d_ws, size_t ws_size,
                              hipStream_t stream) {
    const float* x   = (const float*)d_in[0];
    const int*   ei  = (const int*)d_in[1];
    const int* batch = (const int*)d_in[2];
    const float* w1a = (const float*)d_in[3];
    const float* b1a = (const float*)d_in[4];
    const float* w2a = (const float*)d_in[5];
    const float* b2a = (const float*)d_in[6];
    const float* ga  = (const float*)d_in[7];
    const float* ba  = (const float*)d_in[8];
    const float* w1s = (const float*)d_in[9];
    const float* b1s = (const float*)d_in[10];
    const float* w2s = (const float*)d_in[11];
    const float* b2s = (const float*)d_in[12];
    const float* gs  = (const float*)d_in[13];
    const float* bs  = (const float*)d_in[14];
    const int* src = ei;
    const int* dst = ei + N_EDGES;

    char* ws = (char*)d_ws;
    size_t off = 0;
    auto alloc = [&](size_t bytes) { void* p = ws + off; off += (bytes + 255) & ~(size_t)255; return p; };
    float* A      = (float*)alloc(sizeof(float) * (size_t)N_NODES * HID);
    float* B      = (float*)alloc(sizeof(float) * (size_t)N_NODES * HID);
    int*   rowptr = (int*)alloc(sizeof(int) * (N_NODES + 1));
    int*   deg    = (int*)alloc(sizeof(int) * N_NODES);
    int*   cursor = (int*)alloc(sizeof(int) * N_NODES);
    int*   col    = (int*)alloc(sizeof(int) * N_EDGES);
    int*   bsum   = (int*)alloc(sizeof(int) * 64);
    float* stats  = (float*)alloc(sizeof(float) * 1024);
    // W transposed hi/lo: w1a(256x128) then 5x (256x256)
    constexpr size_t WT_TOT = 32768 + 5 * 65536;
    u16* WtH = (u16*)alloc(sizeof(u16) * WT_TOT);
    u16* WtL = (u16*)alloc(sizeof(u16) * WT_TOT);
    constexpr size_t o1a = 0, o2a = 32768, o1s0 = 98304, o1s1 = 163840, o2s0 = 229376, o2s1 = 294912;
    float* out    = (float*)d_out;
    (void)ws_size; (void)in_sizes; (void)n_in; (void)out_size;

    // ---- weight prep ----
    wsplit_k<<<128, 256, 0, stream>>>(w1a,          WtH + o1a,  WtL + o1a,  128);
    wsplit_k<<<256, 256, 0, stream>>>(w2a,          WtH + o2a,  WtL + o2a,  256);
    wsplit_k<<<256, 256, 0, stream>>>(w1s,          WtH + o1s0, WtL + o1s0, 256);
    wsplit_k<<<256, 256, 0, stream>>>(w1s + 65536,  WtH + o1s1, WtL + o1s1, 256);
    wsplit_k<<<256, 256, 0, stream>>>(w2s,          WtH + o2s0, WtL + o2s0, 256);
    wsplit_k<<<256, 256, 0, stream>>>(w2s + 65536,  WtH + o2s1, WtL + o2s1, 256);

    // ---- CSR build (by dst) ----
    hipMemsetAsync(deg, 0, sizeof(int) * N_NODES, stream);
    hist_k<<<N_EDGES / 256, 256, 0, stream>>>(dst, deg);
    scan_part1<<<SCAN_NB, 256, 0, stream>>>(deg, bsum);
    scan_tops<<<1, 64, 0, stream>>>(bsum, rowptr);
    scan_final<<<SCAN_NB, 256, 0, stream>>>(deg, bsum, rowptr, cursor);
    build_csr<<<N_EDGES / 256, 256, 0, stream>>>(src, dst, cursor, col);

    const int AGG_GRID  = (N_NODES + 3) / 4;     // 12500
    const int GEMM_GRID = (N_NODES + 127) / 128; // 391
    const int BNAP_GRID = N_NODES * 64 / 256;    // 12500

    // ---- layer 1 (x: 128 feats) ----
    aggregate_k<128><<<AGG_GRID, 256, 0, stream>>>(x, rowptr, col, A);
    gemm_mfma<128><<<GEMM_GRID, 256, 0, stream>>>(A, WtH + o1a, WtL + o1a, b1a, B);
    gemm_mfma<256><<<GEMM_GRID, 256, 0, stream>>>(B, WtH + o2a, WtL + o2a, b2a, B);
    hipMemsetAsync(stats, 0, sizeof(float) * 512, stream);
    bn_stats<<<512, 256, 0, stream>>>(B, stats);
    bn_finalize<<<1, 256, 0, stream>>>(stats, ga, ba, stats + 512);
    bn_apply<<<BNAP_GRID, 256, 0, stream>>>(B, stats + 512);

    // ---- layer 2 ----
    aggregate_k<256><<<AGG_GRID, 256, 0, stream>>>(B, rowptr, col, A);
    gemm_mfma<256><<<GEMM_GRID, 256, 0, stream>>>(A, WtH + o1s0, WtL + o1s0, b1s, A);
    gemm_mfma<256><<<GEMM_GRID, 256, 0, stream>>>(A, WtH + o2s0, WtL + o2s0, b2s, A);
    hipMemsetAsync(stats, 0, sizeof(float) * 512, stream);
    bn_stats<<<512, 256, 0, stream>>>(A, stats);
    bn_finalize<<<1, 256, 0, stream>>>(stats, gs, bs, stats + 512);
    bn_apply<<<BNAP_GRID, 256, 0, stream>>>(A, stats + 512);

    // ---- layer 3 ----
    aggregate_k<256><<<AGG_GRID, 256, 0, stream>>>(A, rowptr, col, B);
    gemm_mfma<256><<<GEMM_GRID, 256, 0, stream>>>(B, WtH + o1s1, WtL + o1s1, b1s + 256, B);
    gemm_mfma<256><<<GEMM_GRID, 256, 0, stream>>>(B, WtH + o2s1, WtL + o2s1, b2s + 256, B);
    hipMemsetAsync(stats, 0, sizeof(float) * 512, stream);
    bn_stats<<<512, 256, 0, stream>>>(B, stats);
    bn_finalize<<<1, 256, 0, stream>>>(stats, gs + 256, bs + 256, stats + 512);
    bn_apply<<<BNAP_GRID, 256, 0, stream>>>(B, stats + 512);

    // ---- pool ----
    pool_k<<<N_GRAPHS, 256, 0, stream>>>(B, batch, out);
}

// Round 3
// 701.358 us; speedup vs baseline: 1.6721x; 1.2136x over previous
//
#include <hip/hip_runtime.h>
#include <cstdint>
#include <cstddef>

// GIN 3-layer + BN + mean-pool. R3: BN folded into agg/pool, BN-stats fused
// into GEMM2 epilogue, aggregate edge-loop unrolled x4.

constexpr int N_NODES  = 50000;
constexpr int N_EDGES  = 800000;
constexpr int F_IN     = 128;
constexpr int HID      = 256;
constexpr int N_GRAPHS = 512;
constexpr float BN_EPS = 1e-5f;

constexpr int SCAN_CHUNK = 4096;
constexpr int SCAN_NB    = (N_NODES + SCAN_CHUNK - 1) / SCAN_CHUNK; // 13

typedef unsigned short u16;
typedef u16 u16x8 __attribute__((ext_vector_type(8)));
typedef __bf16 bf16x8 __attribute__((ext_vector_type(8)));
typedef float f32x4 __attribute__((ext_vector_type(4)));

__device__ __forceinline__ u16 f2bf(float f) {
    uint32_t u = __float_as_uint(f);
    uint32_t r = (u + 0x7FFFu + ((u >> 16) & 1u)) >> 16;
    return (u16)r;
}
__device__ __forceinline__ float bf2f(u16 h) {
    return __uint_as_float(((uint32_t)h) << 16);
}

// ---------------- CSR build ----------------
__global__ void hist_k(const int* __restrict__ dst, int* __restrict__ deg) {
    int e = blockIdx.x * 256 + threadIdx.x;
    if (e < N_EDGES) atomicAdd(&deg[dst[e]], 1);
}

__global__ void scan_part1(const int* __restrict__ in, int* __restrict__ bsum) {
    __shared__ int sm[256];
    int t = threadIdx.x;
    int base = blockIdx.x * SCAN_CHUNK + t * 16;
    int s = 0;
#pragma unroll
    for (int j = 0; j < 16; j++) { int idx = base + j; s += (idx < N_NODES) ? in[idx] : 0; }
    sm[t] = s; __syncthreads();
    for (int off = 128; off > 0; off >>= 1) {
        if (t < off) sm[t] += sm[t + off];
        __syncthreads();
    }
    if (t == 0) bsum[blockIdx.x] = sm[0];
}

__global__ void scan_tops(int* __restrict__ bsum, int* __restrict__ rowptr) {
    if (threadIdx.x == 0 && blockIdx.x == 0) {
        int acc = 0;
        for (int i = 0; i < SCAN_NB; i++) { int v = bsum[i]; bsum[i] = acc; acc += v; }
        rowptr[N_NODES] = acc; // == N_EDGES
    }
}

__global__ void scan_final(const int* __restrict__ in, const int* __restrict__ bsum,
                           int* __restrict__ rowptr, int* __restrict__ cursor) {
    __shared__ int sm[256];
    int t = threadIdx.x;
    int base = blockIdx.x * SCAN_CHUNK + t * 16;
    int loc[16]; int s = 0;
#pragma unroll
    for (int j = 0; j < 16; j++) { int idx = base + j; loc[j] = s; s += (idx < N_NODES) ? in[idx] : 0; }
    sm[t] = s; __syncthreads();
    for (int off = 1; off < 256; off <<= 1) {
        int v = (t >= off) ? sm[t - off] : 0;
        __syncthreads();
        sm[t] += v;
        __syncthreads();
    }
    int excl = sm[t] - s + bsum[blockIdx.x];
#pragma unroll
    for (int j = 0; j < 16; j++) {
        int idx = base + j;
        if (idx < N_NODES) { int rp = excl + loc[j]; rowptr[idx] = rp; cursor[idx] = rp; }
    }
}

__global__ void build_csr(const int* __restrict__ src, const int* __restrict__ dst,
                          int* __restrict__ cursor, int* __restrict__ col) {
    int e = blockIdx.x * 256 + threadIdx.x;
    if (e < N_EDGES) {
        int d = dst[e];
        int p = atomicAdd(&cursor[d], 1);
        col[p] = src[e];
    }
}

// -------- aggregation: out[n] = fold( h[n] + sum_{e: dst=n} h[src[e]] ) --------
// FOLD: out = sc * acc + (deg+1) * sh   (BN of PREVIOUS layer folded in; exact)
template <int F, bool FOLD>
__global__ __launch_bounds__(256) void aggregate_k(const float* __restrict__ h,
                                                   const int* __restrict__ rowptr,
                                                   const int* __restrict__ col,
                                                   const float* __restrict__ scsh,
                                                   float* __restrict__ outp) {
    int node = blockIdx.x * 4 + (threadIdx.x >> 6);
    if (node >= N_NODES) return;
    int lane = threadIdx.x & 63;
    int beg = rowptr[node], end = rowptr[node + 1];
    if constexpr (F == 256) {
        const float4* hp = reinterpret_cast<const float4*>(h);
        float4 acc = hp[(size_t)node * 64 + lane];
        int e = beg;
        for (; e + 4 <= end; e += 4) {
            int s0 = col[e], s1 = col[e + 1], s2 = col[e + 2], s3 = col[e + 3];
            float4 v0 = hp[(size_t)s0 * 64 + lane];
            float4 v1 = hp[(size_t)s1 * 64 + lane];
            float4 v2 = hp[(size_t)s2 * 64 + lane];
            float4 v3 = hp[(size_t)s3 * 64 + lane];
            acc.x += (v0.x + v1.x) + (v2.x + v3.x);
            acc.y += (v0.y + v1.y) + (v2.y + v3.y);
            acc.z += (v0.z + v1.z) + (v2.z + v3.z);
            acc.w += (v0.w + v1.w) + (v2.w + v3.w);
        }
        for (; e < end; ++e) {
            int s = col[e];
            float4 v = hp[(size_t)s * 64 + lane];
            acc.x += v.x; acc.y += v.y; acc.z += v.z; acc.w += v.w;
        }
        if constexpr (FOLD) {
            int c4 = lane * 4;
            float4 sc = *reinterpret_cast<const float4*>(&scsh[c4]);
            float4 sh = *reinterpret_cast<const float4*>(&scsh[HID + c4]);
            float m = (float)(end - beg + 1);
            acc.x = acc.x * sc.x + m * sh.x;
            acc.y = acc.y * sc.y + m * sh.y;
            acc.z = acc.z * sc.z + m * sh.z;
            acc.w = acc.w * sc.w + m * sh.w;
        }
        reinterpret_cast<float4*>(outp)[(size_t)node * 64 + lane] = acc;
    } else { // F == 128, no fold (layer-1 input is raw x)
        const float2* hp = reinterpret_cast<const float2*>(h);
        float2 acc = hp[(size_t)node * 64 + lane];
        int e = beg;
        for (; e + 4 <= end; e += 4) {
            int s0 = col[e], s1 = col[e + 1], s2 = col[e + 2], s3 = col[e + 3];
            float2 v0 = hp[(size_t)s0 * 64 + lane];
            float2 v1 = hp[(size_t)s1 * 64 + lane];
            float2 v2 = hp[(size_t)s2 * 64 + lane];
            float2 v3 = hp[(size_t)s3 * 64 + lane];
            acc.x += (v0.x + v1.x) + (v2.x + v3.x);
            acc.y += (v0.y + v1.y) + (v2.y + v3.y);
        }
        for (; e < end; ++e) {
            int s = col[e];
            float2 v = hp[(size_t)s * 64 + lane];
            acc.x += v.x; acc.y += v.y;
        }
        reinterpret_cast<float2*>(outp)[(size_t)node * 64 + lane] = acc;
    }
}

// ---------------- W pre-transpose + bf16 split: Wt[n][k] = hi/lo(W[k][n]) ----------------
__global__ void wsplit_k(const float* __restrict__ W, u16* __restrict__ th,
                         u16* __restrict__ tl, int K) {
    int idx = blockIdx.x * 256 + threadIdx.x; // total K*256
    int n = idx & 255, k = idx >> 8;
    float f = W[(size_t)k * 256 + n];
    u16 h = f2bf(f);
    th[(size_t)n * K + k] = h;
    tl[(size_t)n * K + k] = f2bf(f - bf2f(h));
}

// ---------------- split-bf16 MFMA GEMM: C[M][256] = relu(A[M][K] @ W + bias) ----------------
// Block: 128 rows x 256 cols (full N -> in-place safe). 4 waves, each 64x128.
// acc += Ahi*Whi + Alo*Whi + Ahi*Wlo  (lo*lo dropped, ~2^-18 rel err)
// STATS: accumulate per-column sum / sumsq of the relu output into stats[0..255]/[256..511].
template <int K, bool STATS>
__global__ __launch_bounds__(256, 2) void gemm_mfma(const float* __restrict__ A,
                                                    const u16* __restrict__ Wth,
                                                    const u16* __restrict__ Wtl,
                                                    const float* __restrict__ bias,
                                                    float* __restrict__ C,
                                                    float* __restrict__ stats) {
    constexpr int BM = 128, BK = 32;
    __shared__ alignas(16) u16 Ah[BM * BK];
    __shared__ alignas(16) u16 Al[BM * BK];
    __shared__ alignas(16) u16 Bh[HID * BK];
    __shared__ alignas(16) u16 Bl[HID * BK];
    __shared__ float smsum[HID];
    __shared__ float smsq[HID];

    const int tid  = threadIdx.x;
    const int r0   = blockIdx.x * BM;
    const int lane = tid & 63, wid = tid >> 6;
    const int wm = wid >> 1, wn = wid & 1;
    const int l15 = lane & 15, kg = lane >> 4;

    const int arow = tid >> 1, ahalf = tid & 1;
    const bool avalid = (r0 + arow) < N_NODES;
    const float* aptr = A + (size_t)(r0 + arow) * K + ahalf * 16;
    const u16* bhptr = Wth + (size_t)tid * K;
    const u16* blptr = Wtl + (size_t)tid * K;

    f32x4 acc[4][8];
#pragma unroll
    for (int i = 0; i < 4; i++)
#pragma unroll
        for (int j = 0; j < 8; j++) acc[i][j] = (f32x4){0.f, 0.f, 0.f, 0.f};

    for (int k0 = 0; k0 < K; k0 += BK) {
        // ---- stage A tile (128 x 32 fp32 -> hi/lo bf16, chunk-swizzled) ----
        float av[16];
        if (avalid) {
#pragma unroll
            for (int j = 0; j < 4; j++)
                *reinterpret_cast<float4*>(&av[j * 4]) =
                    *reinterpret_cast<const float4*>(aptr + k0 + j * 4);
        } else {
#pragma unroll
            for (int i = 0; i < 16; i++) av[i] = 0.f;
        }
        u16x8 vh[2], vl[2];
#pragma unroll
        for (int j = 0; j < 2; j++)
#pragma unroll
            for (int i = 0; i < 8; i++) {
                float f = av[j * 8 + i];
                u16 h = f2bf(f);
                vh[j][i] = h;
                vl[j][i] = f2bf(f - bf2f(h));
            }
#pragma unroll
        for (int j = 0; j < 2; j++) {
            int c = ahalf * 2 + j;
            int off = arow * 64 + ((c ^ ((arow >> 1) & 3)) << 4);
            *reinterpret_cast<u16x8*>((char*)Ah + off) = vh[j];
            *reinterpret_cast<u16x8*>((char*)Al + off) = vl[j];
        }
        // ---- stage B tile (Wt[n][k] bf16, n = tid, chunk-swizzled) ----
#pragma unroll
        for (int j = 0; j < 4; j++) {
            u16x8 v = *reinterpret_cast<const u16x8*>(bhptr + k0 + j * 8);
            int off = tid * 64 + ((j ^ ((tid >> 1) & 3)) << 4);
            *reinterpret_cast<u16x8*>((char*)Bh + off) = v;
        }
#pragma unroll
        for (int j = 0; j < 4; j++) {
            u16x8 v = *reinterpret_cast<const u16x8*>(blptr + k0 + j * 8);
            int off = tid * 64 + ((j ^ ((tid >> 1) & 3)) << 4);
            *reinterpret_cast<u16x8*>((char*)Bl + off) = v;
        }
        __syncthreads();
        // ---- MFMA: wave tile 64x128, 96 mfma per K-step ----
        bf16x8 ah[4], al[4];
#pragma unroll
        for (int mi = 0; mi < 4; mi++) {
            int r = wm * 64 + mi * 16 + l15;
            int off = r * 64 + ((kg ^ ((r >> 1) & 3)) << 4);
            ah[mi] = __builtin_bit_cast(bf16x8, *reinterpret_cast<const u16x8*>((const char*)Ah + off));
            al[mi] = __builtin_bit_cast(bf16x8, *reinterpret_cast<const u16x8*>((const char*)Al + off));
        }
#pragma unroll
        for (int ni = 0; ni < 8; ni++) {
            int n = wn * 128 + ni * 16 + l15;
            int off = n * 64 + ((kg ^ ((n >> 1) & 3)) << 4);
            bf16x8 bh = __builtin_bit_cast(bf16x8, *reinterpret_cast<const u16x8*>((const char*)Bh + off));
            bf16x8 bl = __builtin_bit_cast(bf16x8, *reinterpret_cast<const u16x8*>((const char*)Bl + off));
#pragma unroll
            for (int mi = 0; mi < 4; mi++) {
                acc[mi][ni] = __builtin_amdgcn_mfma_f32_16x16x32_bf16(ah[mi], bh, acc[mi][ni], 0, 0, 0);
                acc[mi][ni] = __builtin_amdgcn_mfma_f32_16x16x32_bf16(al[mi], bh, acc[mi][ni], 0, 0, 0);
                acc[mi][ni] = __builtin_amdgcn_mfma_f32_16x16x32_bf16(ah[mi], bl, acc[mi][ni], 0, 0, 0);
            }
        }
        __syncthreads();
    }
    // ---- epilogue: bias + relu + store; optional per-column stats ----
    if constexpr (STATS) {
        smsum[tid] = 0.f;
        smsq[tid]  = 0.f;
        __syncthreads();
    }
    float bv[8];
#pragma unroll
    for (int ni = 0; ni < 8; ni++) bv[ni] = bias[wn * 128 + ni * 16 + l15];
    float ps[8] = {}, pq[8] = {};
#pragma unroll
    for (int mi = 0; mi < 4; mi++) {
        int rowb = r0 + wm * 64 + mi * 16 + kg * 4;
#pragma unroll
        for (int rr = 0; rr < 4; rr++) {
            int row = rowb + rr;
            if (row < N_NODES) {
                float* cp = C + (size_t)row * HID + wn * 128 + l15;
#pragma unroll
                for (int ni = 0; ni < 8; ni++) {
                    float v = fmaxf(acc[mi][ni][rr] + bv[ni], 0.f);
                    cp[ni * 16] = v;
                    if constexpr (STATS) { ps[ni] += v; pq[ni] += v * v; }
                }
            }
        }
    }
    if constexpr (STATS) {
#pragma unroll
        for (int ni = 0; ni < 8; ni++) {
            int c = wn * 128 + ni * 16 + l15;
            atomicAdd(&smsum[c], ps[ni]);
            atomicAdd(&smsq[c], pq[ni]);
        }
        __syncthreads();
        atomicAdd(&stats[tid], smsum[tid]);
        atomicAdd(&stats[HID + tid], smsq[tid]);
    }
}

// ---------------- BN finalize: stats -> scale/shift ----------------
__global__ void bn_finalize(const float* __restrict__ stats, const float* __restrict__ gamma,
                            const float* __restrict__ beta, float* __restrict__ scsh) {
    int c = threadIdx.x;
    float mu  = stats[c] * (1.f / N_NODES);
    float var = stats[HID + c] * (1.f / N_NODES) - mu * mu;
    float g = gamma[c] * rsqrtf(var + BN_EPS);
    scsh[c] = g;
    scsh[HID + c] = beta[c] - mu * g;
}

// ---------------- mean pool (batch sorted), BN of layer-3 folded in ----------------
__device__ __forceinline__ int lowerb(const int* a, int key) {
    int lo = 0, hi = N_NODES;
    while (lo < hi) { int mid = (lo + hi) >> 1; if (a[mid] < key) lo = mid + 1; else hi = mid; }
    return lo;
}

__global__ void pool_k(const float* __restrict__ h, const int* __restrict__ batch,
                       const float* __restrict__ scsh, float* __restrict__ out) {
    __shared__ int bnd[2];
    int g = blockIdx.x;
    if (threadIdx.x == 0) bnd[0] = lowerb(batch, g);
    if (threadIdx.x == 1) bnd[1] = lowerb(batch, g + 1);
    __syncthreads();
    int lo = bnd[0], hi = bnd[1];
    int c = threadIdx.x;
    float s = 0.f;
    for (int r = lo; r < hi; ++r) s += h[(size_t)r * HID + c];
    int cnt = hi - lo;
    float v = (cnt > 0) ? (scsh[c] * (s / (float)cnt) + scsh[HID + c]) : 0.f;
    out[(size_t)g * HID + c] = v;
}

// ---------------- launch ----------------
extern "C" void kernel_launch(void* const* d_in, const int* in_sizes, int n_in,
                              void* d_out, int out_size, void* d_ws, size_t ws_size,
                              hipStream_t stream) {
    const float* x   = (const float*)d_in[0];
    const int*   ei  = (const int*)d_in[1];
    const int* batch = (const int*)d_in[2];
    const float* w1a = (const float*)d_in[3];
    const float* b1a = (const float*)d_in[4];
    const float* w2a = (const float*)d_in[5];
    const float* b2a = (const float*)d_in[6];
    const float* ga  = (const float*)d_in[7];
    const float* ba  = (const float*)d_in[8];
    const float* w1s = (const float*)d_in[9];
    const float* b1s = (const float*)d_in[10];
    const float* w2s = (const float*)d_in[11];
    const float* b2s = (const float*)d_in[12];
    const float* gs  = (const float*)d_in[13];
    const float* bs  = (const float*)d_in[14];
    const int* src = ei;
    const int* dst = ei + N_EDGES;

    char* ws = (char*)d_ws;
    size_t off = 0;
    auto alloc = [&](size_t bytes) { void* p = ws + off; off += (bytes + 255) & ~(size_t)255; return p; };
    float* A      = (float*)alloc(sizeof(float) * (size_t)N_NODES * HID);
    float* B      = (float*)alloc(sizeof(float) * (size_t)N_NODES * HID);
    int*   rowptr = (int*)alloc(sizeof(int) * (N_NODES + 1));
    int*   deg    = (int*)alloc(sizeof(int) * N_NODES);
    int*   cursor = (int*)alloc(sizeof(int) * N_NODES);
    int*   col    = (int*)alloc(sizeof(int) * N_EDGES);
    int*   bsum   = (int*)alloc(sizeof(int) * 64);
    float* stats  = (float*)alloc(sizeof(float) * 512 * 3);  // sum||sq per layer
    float* scsh   = (float*)alloc(sizeof(float) * 512 * 3);  // scale||shift per layer
    constexpr size_t WT_TOT = 32768 + 5 * 65536;
    u16* WtH = (u16*)alloc(sizeof(u16) * WT_TOT);
    u16* WtL = (u16*)alloc(sizeof(u16) * WT_TOT);
    constexpr size_t o1a = 0, o2a = 32768, o1s0 = 98304, o1s1 = 163840, o2s0 = 229376, o2s1 = 294912;
    float* out    = (float*)d_out;
    (void)ws_size; (void)in_sizes; (void)n_in; (void)out_size;

    // ---- weight prep ----
    wsplit_k<<<128, 256, 0, stream>>>(w1a,          WtH + o1a,  WtL + o1a,  128);
    wsplit_k<<<256, 256, 0, stream>>>(w2a,          WtH + o2a,  WtL + o2a,  256);
    wsplit_k<<<256, 256, 0, stream>>>(w1s,          WtH + o1s0, WtL + o1s0, 256);
    wsplit_k<<<256, 256, 0, stream>>>(w1s + 65536,  WtH + o1s1, WtL + o1s1, 256);
    wsplit_k<<<256, 256, 0, stream>>>(w2s,          WtH + o2s0, WtL + o2s0, 256);
    wsplit_k<<<256, 256, 0, stream>>>(w2s + 65536,  WtH + o2s1, WtL + o2s1, 256);
    hipMemsetAsync(stats, 0, sizeof(float) * 512 * 3, stream);

    // ---- CSR build (by dst) ----
    hipMemsetAsync(deg, 0, sizeof(int) * N_NODES, stream);
    hist_k<<<N_EDGES / 256, 256, 0, stream>>>(dst, deg);
    scan_part1<<<SCAN_NB, 256, 0, stream>>>(deg, bsum);
    scan_tops<<<1, 64, 0, stream>>>(bsum, rowptr);
    scan_final<<<SCAN_NB, 256, 0, stream>>>(deg, bsum, rowptr, cursor);
    build_csr<<<N_EDGES / 256, 256, 0, stream>>>(src, dst, cursor, col);

    const int AGG_GRID  = (N_NODES + 3) / 4;     // 12500
    const int GEMM_GRID = (N_NODES + 127) / 128; // 391

    // ---- layer 1 ----
    aggregate_k<128, false><<<AGG_GRID, 256, 0, stream>>>(x, rowptr, col, nullptr, A);
    gemm_mfma<128, false><<<GEMM_GRID, 256, 0, stream>>>(A, WtH + o1a, WtL + o1a, b1a, B, nullptr);
    gemm_mfma<256, true><<<GEMM_GRID, 256, 0, stream>>>(B, WtH + o2a, WtL + o2a, b2a, B, stats);
    bn_finalize<<<1, 256, 0, stream>>>(stats, ga, ba, scsh);

    // ---- layer 2 (BN1 folded into aggregate) ----
    aggregate_k<256, true><<<AGG_GRID, 256, 0, stream>>>(B, rowptr, col, scsh, A);
    gemm_mfma<256, false><<<GEMM_GRID, 256, 0, stream>>>(A, WtH + o1s0, WtL + o1s0, b1s, A, nullptr);
    gemm_mfma<256, true><<<GEMM_GRID, 256, 0, stream>>>(A, WtH + o2s0, WtL + o2s0, b2s, A, stats + 512);
    bn_finalize<<<1, 256, 0, stream>>>(stats + 512, gs, bs, scsh + 512);

    // ---- layer 3 (BN2 folded into aggregate) ----
    aggregate_k<256, true><<<AGG_GRID, 256, 0, stream>>>(A, rowptr, col, scsh + 512, B);
    gemm_mfma<256, false><<<GEMM_GRID, 256, 0, stream>>>(B, WtH + o1s1, WtL + o1s1, b1s + 256, B, nullptr);
    gemm_mfma<256, true><<<GEMM_GRID, 256, 0, stream>>>(B, WtH + o2s1, WtL + o2s1, b2s + 256, B, stats + 1024);
    bn_finalize<<<1, 256, 0, stream>>>(stats + 1024, gs + 256, bs + 256, scsh + 1024);

    // ---- pool (BN3 folded in) ----
    pool_k<<<N_GRAPHS, 256, 0, stream>>>(B, batch, scsh + 1024, out);
}

// Round 4
// 497.467 us; speedup vs baseline: 2.3574x; 1.4099x over previous
//
#include <hip/hip_runtime.h>
#include <cstdint>
#include <cstddef>

// GIN 3-layer + BN + mean-pool. R4: bf16 node features (half agg traffic),
// bf16-A MFMA GEMM (2-plane W, 64 mfma/K-step), BN folded, stats fused.

constexpr int N_NODES  = 50000;
constexpr int N_EDGES  = 800000;
constexpr int F_IN     = 128;
constexpr int HID      = 256;
constexpr int N_GRAPHS = 512;
constexpr float BN_EPS = 1e-5f;

constexpr int SCAN_CHUNK = 4096;
constexpr int SCAN_NB    = (N_NODES + SCAN_CHUNK - 1) / SCAN_CHUNK; // 13

typedef unsigned short u16;
typedef u16 u16x2 __attribute__((ext_vector_type(2)));
typedef u16 u16x4 __attribute__((ext_vector_type(4)));
typedef u16 u16x8 __attribute__((ext_vector_type(8)));
typedef __bf16 bf16x8 __attribute__((ext_vector_type(8)));
typedef float f32x4 __attribute__((ext_vector_type(4)));

__device__ __forceinline__ u16 f2bf(float f) {
    uint32_t u = __float_as_uint(f);
    uint32_t r = (u + 0x7FFFu + ((u >> 16) & 1u)) >> 16;
    return (u16)r;
}
__device__ __forceinline__ float bf2f(u16 h) {
    return __uint_as_float(((uint32_t)h) << 16);
}

// ---------------- x -> bf16 ----------------
__global__ void f2bf_k(const float* __restrict__ in, u16* __restrict__ outp, int n8) {
    int i = blockIdx.x * 256 + threadIdx.x;
    if (i >= n8) return;
    float4 a = reinterpret_cast<const float4*>(in)[i * 2];
    float4 b = reinterpret_cast<const float4*>(in)[i * 2 + 1];
    u16x8 v;
    v[0] = f2bf(a.x); v[1] = f2bf(a.y); v[2] = f2bf(a.z); v[3] = f2bf(a.w);
    v[4] = f2bf(b.x); v[5] = f2bf(b.y); v[6] = f2bf(b.z); v[7] = f2bf(b.w);
    reinterpret_cast<u16x8*>(outp)[i] = v;
}

// ---------------- CSR build ----------------
__global__ void hist_k(const int* __restrict__ dst, int* __restrict__ deg) {
    int e = blockIdx.x * 256 + threadIdx.x;
    if (e < N_EDGES) atomicAdd(&deg[dst[e]], 1);
}

__global__ void scan_part1(const int* __restrict__ in, int* __restrict__ bsum) {
    __shared__ int sm[256];
    int t = threadIdx.x;
    int base = blockIdx.x * SCAN_CHUNK + t * 16;
    int s = 0;
#pragma unroll
    for (int j = 0; j < 16; j++) { int idx = base + j; s += (idx < N_NODES) ? in[idx] : 0; }
    sm[t] = s; __syncthreads();
    for (int off = 128; off > 0; off >>= 1) {
        if (t < off) sm[t] += sm[t + off];
        __syncthreads();
    }
    if (t == 0) bsum[blockIdx.x] = sm[0];
}

__global__ void scan_tops(int* __restrict__ bsum, int* __restrict__ rowptr) {
    if (threadIdx.x == 0 && blockIdx.x == 0) {
        int acc = 0;
        for (int i = 0; i < SCAN_NB; i++) { int v = bsum[i]; bsum[i] = acc; acc += v; }
        rowptr[N_NODES] = acc; // == N_EDGES
    }
}

__global__ void scan_final(const int* __restrict__ in, const int* __restrict__ bsum,
                           int* __restrict__ rowptr, int* __restrict__ cursor) {
    __shared__ int sm[256];
    int t = threadIdx.x;
    int base = blockIdx.x * SCAN_CHUNK + t * 16;
    int loc[16]; int s = 0;
#pragma unroll
    for (int j = 0; j < 16; j++) { int idx = base + j; loc[j] = s; s += (idx < N_NODES) ? in[idx] : 0; }
    sm[t] = s; __syncthreads();
    for (int off = 1; off < 256; off <<= 1) {
        int v = (t >= off) ? sm[t - off] : 0;
        __syncthreads();
        sm[t] += v;
        __syncthreads();
    }
    int excl = sm[t] - s + bsum[blockIdx.x];
#pragma unroll
    for (int j = 0; j < 16; j++) {
        int idx = base + j;
        if (idx < N_NODES) { int rp = excl + loc[j]; rowptr[idx] = rp; cursor[idx] = rp; }
    }
}

__global__ void build_csr(const int* __restrict__ src, const int* __restrict__ dst,
                          int* __restrict__ cursor, int* __restrict__ col) {
    int e = blockIdx.x * 256 + threadIdx.x;
    if (e < N_EDGES) {
        int d = dst[e];
        int p = atomicAdd(&cursor[d], 1);
        col[p] = src[e];
    }
}

// -------- aggregation (bf16 in/out, fp32 accum) --------
// out[n] = fold( h[n] + sum_{e: dst=n} h[src[e]] );  FOLD: sc*acc + (deg+1)*sh
template <int F, bool FOLD>
__global__ __launch_bounds__(256) void aggregate_k(const u16* __restrict__ h,
                                                   const int* __restrict__ rowptr,
                                                   const int* __restrict__ col,
                                                   const float* __restrict__ scsh,
                                                   u16* __restrict__ outp) {
    int node = blockIdx.x * 4 + (threadIdx.x >> 6);
    if (node >= N_NODES) return;
    int lane = threadIdx.x & 63;
    int beg = rowptr[node], end = rowptr[node + 1];
    if constexpr (F == 256) {
        const u16x4* hp = reinterpret_cast<const u16x4*>(h); // row stride 64
        u16x4 sv = hp[(size_t)node * 64 + lane];
        float acc[4] = {bf2f(sv[0]), bf2f(sv[1]), bf2f(sv[2]), bf2f(sv[3])};
        int e = beg;
        for (; e + 4 <= end; e += 4) {
            int s0 = col[e], s1 = col[e + 1], s2 = col[e + 2], s3 = col[e + 3];
            u16x4 v0 = hp[(size_t)s0 * 64 + lane];
            u16x4 v1 = hp[(size_t)s1 * 64 + lane];
            u16x4 v2 = hp[(size_t)s2 * 64 + lane];
            u16x4 v3 = hp[(size_t)s3 * 64 + lane];
#pragma unroll
            for (int i = 0; i < 4; i++)
                acc[i] += (bf2f(v0[i]) + bf2f(v1[i])) + (bf2f(v2[i]) + bf2f(v3[i]));
        }
        for (; e < end; ++e) {
            int s = col[e];
            u16x4 v = hp[(size_t)s * 64 + lane];
#pragma unroll
            for (int i = 0; i < 4; i++) acc[i] += bf2f(v[i]);
        }
        if constexpr (FOLD) {
            int c4 = lane * 4;
            float4 sc = *reinterpret_cast<const float4*>(&scsh[c4]);
            float4 sh = *reinterpret_cast<const float4*>(&scsh[HID + c4]);
            float m = (float)(end - beg + 1);
            acc[0] = acc[0] * sc.x + m * sh.x;
            acc[1] = acc[1] * sc.y + m * sh.y;
            acc[2] = acc[2] * sc.z + m * sh.z;
            acc[3] = acc[3] * sc.w + m * sh.w;
        }
        u16x4 r;
#pragma unroll
        for (int i = 0; i < 4; i++) r[i] = f2bf(acc[i]);
        reinterpret_cast<u16x4*>(outp)[(size_t)node * 64 + lane] = r;
    } else { // F == 128, no fold (layer-1 input)
        const u16x2* hp = reinterpret_cast<const u16x2*>(h); // row stride 64
        u16x2 sv = hp[(size_t)node * 64 + lane];
        float acc[2] = {bf2f(sv[0]), bf2f(sv[1])};
        int e = beg;
        for (; e + 4 <= end; e += 4) {
            int s0 = col[e], s1 = col[e + 1], s2 = col[e + 2], s3 = col[e + 3];
            u16x2 v0 = hp[(size_t)s0 * 64 + lane];
            u16x2 v1 = hp[(size_t)s1 * 64 + lane];
            u16x2 v2 = hp[(size_t)s2 * 64 + lane];
            u16x2 v3 = hp[(size_t)s3 * 64 + lane];
#pragma unroll
            for (int i = 0; i < 2; i++)
                acc[i] += (bf2f(v0[i]) + bf2f(v1[i])) + (bf2f(v2[i]) + bf2f(v3[i]));
        }
        for (; e < end; ++e) {
            int s = col[e];
            u16x2 v = hp[(size_t)s * 64 + lane];
#pragma unroll
            for (int i = 0; i < 2; i++) acc[i] += bf2f(v[i]);
        }
        u16x2 r;
        r[0] = f2bf(acc[0]); r[1] = f2bf(acc[1]);
        reinterpret_cast<u16x2*>(outp)[(size_t)node * 64 + lane] = r;
    }
}

// ---------------- W pre-transpose + bf16 split: Wt[n][k] = hi/lo(W[k][n]) ----------------
__global__ void wsplit_k(const float* __restrict__ W, u16* __restrict__ th,
                         u16* __restrict__ tl, int K) {
    int idx = blockIdx.x * 256 + threadIdx.x; // total K*256
    int n = idx & 255, k = idx >> 8;
    float f = W[(size_t)k * 256 + n];
    u16 h = f2bf(f);
    th[(size_t)n * K + k] = h;
    tl[(size_t)n * K + k] = f2bf(f - bf2f(h));
}

// ------- MFMA GEMM: C[M][256] = bf16(relu(A[M][K] @ W + bias)), A bf16 -------
// Block 128 rows x 256 cols (in-place safe). 4 waves, each 64x128.
// acc += A*Whi + A*Wlo  (W fp32-grade; A carries bf16 storage rounding)
template <int K, bool STATS>
__global__ __launch_bounds__(256, 2) void gemm_mfma(const u16* __restrict__ A,
                                                    const u16* __restrict__ Wth,
                                                    const u16* __restrict__ Wtl,
                                                    const float* __restrict__ bias,
                                                    u16* __restrict__ C,
                                                    float* __restrict__ stats) {
    constexpr int BM = 128, BK = 32;
    __shared__ alignas(16) u16 Ah[BM * BK];
    __shared__ alignas(16) u16 Bh[HID * BK];
    __shared__ alignas(16) u16 Bl[HID * BK];
    __shared__ float smsum[HID];
    __shared__ float smsq[HID];

    const int tid  = threadIdx.x;
    const int r0   = blockIdx.x * BM;
    const int lane = tid & 63, wid = tid >> 6;
    const int wm = wid >> 1, wn = wid & 1;
    const int l15 = lane & 15, kg = lane >> 4;

    const int arow = tid >> 1, ahalf = tid & 1;
    const bool avalid = (r0 + arow) < N_NODES;
    const u16* aptr = A + (size_t)(r0 + arow) * K + ahalf * 16;
    const u16* bhptr = Wth + (size_t)tid * K;
    const u16* blptr = Wtl + (size_t)tid * K;

    f32x4 acc[4][8];
#pragma unroll
    for (int i = 0; i < 4; i++)
#pragma unroll
        for (int j = 0; j < 8; j++) acc[i][j] = (f32x4){0.f, 0.f, 0.f, 0.f};

    for (int k0 = 0; k0 < K; k0 += BK) {
        // ---- stage A tile (128 x 32 bf16, chunk-swizzled) ----
        u16x8 av[2];
        if (avalid) {
            av[0] = *reinterpret_cast<const u16x8*>(aptr + k0);
            av[1] = *reinterpret_cast<const u16x8*>(aptr + k0 + 8);
        } else {
            av[0] = (u16x8){0, 0, 0, 0, 0, 0, 0, 0};
            av[1] = av[0];
        }
#pragma unroll
        for (int j = 0; j < 2; j++) {
            int c = ahalf * 2 + j;
            int off = arow * 64 + ((c ^ ((arow >> 1) & 3)) << 4);
            *reinterpret_cast<u16x8*>((char*)Ah + off) = av[j];
        }
        // ---- stage B tile (Wt[n][k] hi/lo, n = tid, chunk-swizzled) ----
#pragma unroll
        for (int j = 0; j < 4; j++) {
            u16x8 v = *reinterpret_cast<const u16x8*>(bhptr + k0 + j * 8);
            int off = tid * 64 + ((j ^ ((tid >> 1) & 3)) << 4);
            *reinterpret_cast<u16x8*>((char*)Bh + off) = v;
        }
#pragma unroll
        for (int j = 0; j < 4; j++) {
            u16x8 v = *reinterpret_cast<const u16x8*>(blptr + k0 + j * 8);
            int off = tid * 64 + ((j ^ ((tid >> 1) & 3)) << 4);
            *reinterpret_cast<u16x8*>((char*)Bl + off) = v;
        }
        __syncthreads();
        // ---- MFMA: wave tile 64x128, 64 mfma per K-step ----
        bf16x8 ah[4];
#pragma unroll
        for (int mi = 0; mi < 4; mi++) {
            int r = wm * 64 + mi * 16 + l15;
            int off = r * 64 + ((kg ^ ((r >> 1) & 3)) << 4);
            ah[mi] = __builtin_bit_cast(bf16x8, *reinterpret_cast<const u16x8*>((const char*)Ah + off));
        }
#pragma unroll
        for (int ni = 0; ni < 8; ni++) {
            int n = wn * 128 + ni * 16 + l15;
            int off = n * 64 + ((kg ^ ((n >> 1) & 3)) << 4);
            bf16x8 bh = __builtin_bit_cast(bf16x8, *reinterpret_cast<const u16x8*>((const char*)Bh + off));
            bf16x8 bl = __builtin_bit_cast(bf16x8, *reinterpret_cast<const u16x8*>((const char*)Bl + off));
#pragma unroll
            for (int mi = 0; mi < 4; mi++) {
                acc[mi][ni] = __builtin_amdgcn_mfma_f32_16x16x32_bf16(ah[mi], bh, acc[mi][ni], 0, 0, 0);
                acc[mi][ni] = __builtin_amdgcn_mfma_f32_16x16x32_bf16(ah[mi], bl, acc[mi][ni], 0, 0, 0);
            }
        }
        __syncthreads();
    }
    // ---- epilogue: bias + relu + bf16 store; optional per-column stats ----
    if constexpr (STATS) {
        smsum[tid] = 0.f;
        smsq[tid]  = 0.f;
        __syncthreads();
    }
    float bv[8];
#pragma unroll
    for (int ni = 0; ni < 8; ni++) bv[ni] = bias[wn * 128 + ni * 16 + l15];
    float ps[8] = {}, pq[8] = {};
#pragma unroll
    for (int mi = 0; mi < 4; mi++) {
        int rowb = r0 + wm * 64 + mi * 16 + kg * 4;
#pragma unroll
        for (int rr = 0; rr < 4; rr++) {
            int row = rowb + rr;
            if (row < N_NODES) {
                u16* cp = C + (size_t)row * HID + wn * 128 + l15;
#pragma unroll
                for (int ni = 0; ni < 8; ni++) {
                    float v = fmaxf(acc[mi][ni][rr] + bv[ni], 0.f);
                    cp[ni * 16] = f2bf(v);
                    if constexpr (STATS) { ps[ni] += v; pq[ni] += v * v; }
                }
            }
        }
    }
    if constexpr (STATS) {
#pragma unroll
        for (int ni = 0; ni < 8; ni++) {
            int c = wn * 128 + ni * 16 + l15;
            atomicAdd(&smsum[c], ps[ni]);
            atomicAdd(&smsq[c], pq[ni]);
        }
        __syncthreads();
        atomicAdd(&stats[tid], smsum[tid]);
        atomicAdd(&stats[HID + tid], smsq[tid]);
    }
}

// ---------------- BN finalize: stats -> scale/shift ----------------
__global__ void bn_finalize(const float* __restrict__ stats, const float* __restrict__ gamma,
                            const float* __restrict__ beta, float* __restrict__ scsh) {
    int c = threadIdx.x;
    float mu  = stats[c] * (1.f / N_NODES);
    float var = stats[HID + c] * (1.f / N_NODES) - mu * mu;
    float g = gamma[c] * rsqrtf(var + BN_EPS);
    scsh[c] = g;
    scsh[HID + c] = beta[c] - mu * g;
}

// ---------------- mean pool (batch sorted), layer-3 BN folded ----------------
__device__ __forceinline__ int lowerb(const int* a, int key) {
    int lo = 0, hi = N_NODES;
    while (lo < hi) { int mid = (lo + hi) >> 1; if (a[mid] < key) lo = mid + 1; else hi = mid; }
    return lo;
}

__global__ void pool_k(const u16* __restrict__ h, const int* __restrict__ batch,
                       const float* __restrict__ scsh, float* __restrict__ out) {
    __shared__ int bnd[2];
    int g = blockIdx.x;
    if (threadIdx.x == 0) bnd[0] = lowerb(batch, g);
    if (threadIdx.x == 1) bnd[1] = lowerb(batch, g + 1);
    __syncthreads();
    int lo = bnd[0], hi = bnd[1];
    int c = threadIdx.x;
    float s = 0.f;
    for (int r = lo; r < hi; ++r) s += bf2f(h[(size_t)r * HID + c]);
    int cnt = hi - lo;
    float v = (cnt > 0) ? (scsh[c] * (s / (float)cnt) + scsh[HID + c]) : 0.f;
    out[(size_t)g * HID + c] = v;
}

// ---------------- launch ----------------
extern "C" void kernel_launch(void* const* d_in, const int* in_sizes, int n_in,
                              void* d_out, int out_size, void* d_ws, size_t ws_size,
                              hipStream_t stream) {
    const float* x   = (const float*)d_in[0];
    const int*   ei  = (const int*)d_in[1];
    const int* batch = (const int*)d_in[2];
    const float* w1a = (const float*)d_in[3];
    const float* b1a = (const float*)d_in[4];
    const float* w2a = (const float*)d_in[5];
    const float* b2a = (const float*)d_in[6];
    const float* ga  = (const float*)d_in[7];
    const float* ba  = (const float*)d_in[8];
    const float* w1s = (const float*)d_in[9];
    const float* b1s = (const float*)d_in[10];
    const float* w2s = (const float*)d_in[11];
    const float* b2s = (const float*)d_in[12];
    const float* gs  = (const float*)d_in[13];
    const float* bs  = (const float*)d_in[14];
    const int* src = ei;
    const int* dst = ei + N_EDGES;

    char* ws = (char*)d_ws;
    size_t off = 0;
    auto alloc = [&](size_t bytes) { void* p = ws + off; off += (bytes + 255) & ~(size_t)255; return p; };
    u16* A      = (u16*)alloc(sizeof(u16) * (size_t)N_NODES * HID);
    u16* B      = (u16*)alloc(sizeof(u16) * (size_t)N_NODES * HID);
    u16* Xb     = (u16*)alloc(sizeof(u16) * (size_t)N_NODES * F_IN);
    int* rowptr = (int*)alloc(sizeof(int) * (N_NODES + 1));
    int* deg    = (int*)alloc(sizeof(int) * N_NODES);
    int* cursor = (int*)alloc(sizeof(int) * N_NODES);
    int* col    = (int*)alloc(sizeof(int) * N_EDGES);
    int* bsum   = (int*)alloc(sizeof(int) * 64);
    float* stats  = (float*)alloc(sizeof(float) * 512 * 3);  // sum||sq per layer
    float* scsh   = (float*)alloc(sizeof(float) * 512 * 3);  // scale||shift per layer
    constexpr size_t WT_TOT = 32768 + 5 * 65536;
    u16* WtH = (u16*)alloc(sizeof(u16) * WT_TOT);
    u16* WtL = (u16*)alloc(sizeof(u16) * WT_TOT);
    constexpr size_t o1a = 0, o2a = 32768, o1s0 = 98304, o1s1 = 163840, o2s0 = 229376, o2s1 = 294912;
    float* out    = (float*)d_out;
    (void)ws_size; (void)in_sizes; (void)n_in; (void)out_size;

    // ---- input/weight prep ----
    f2bf_k<<<(N_NODES * F_IN / 8 + 255) / 256, 256, 0, stream>>>(x, Xb, N_NODES * F_IN / 8);
    wsplit_k<<<128, 256, 0, stream>>>(w1a,          WtH + o1a,  WtL + o1a,  128);
    wsplit_k<<<256, 256, 0, stream>>>(w2a,          WtH + o2a,  WtL + o2a,  256);
    wsplit_k<<<256, 256, 0, stream>>>(w1s,          WtH + o1s0, WtL + o1s0, 256);
    wsplit_k<<<256, 256, 0, stream>>>(w1s + 65536,  WtH + o1s1, WtL + o1s1, 256);
    wsplit_k<<<256, 256, 0, stream>>>(w2s,          WtH + o2s0, WtL + o2s0, 256);
    wsplit_k<<<256, 256, 0, stream>>>(w2s + 65536,  WtH + o2s1, WtL + o2s1, 256);
    hipMemsetAsync(stats, 0, sizeof(float) * 512 * 3, stream);

    // ---- CSR build (by dst) ----
    hipMemsetAsync(deg, 0, sizeof(int) * N_NODES, stream);
    hist_k<<<N_EDGES / 256, 256, 0, stream>>>(dst, deg);
    scan_part1<<<SCAN_NB, 256, 0, stream>>>(deg, bsum);
    scan_tops<<<1, 64, 0, stream>>>(bsum, rowptr);
    scan_final<<<SCAN_NB, 256, 0, stream>>>(deg, bsum, rowptr, cursor);
    build_csr<<<N_EDGES / 256, 256, 0, stream>>>(src, dst, cursor, col);

    const int AGG_GRID  = (N_NODES + 3) / 4;     // 12500
    const int GEMM_GRID = (N_NODES + 127) / 128; // 391

    // ---- layer 1 ----
    aggregate_k<128, false><<<AGG_GRID, 256, 0, stream>>>(Xb, rowptr, col, nullptr, A);
    gemm_mfma<128, false><<<GEMM_GRID, 256, 0, stream>>>(A, WtH + o1a, WtL + o1a, b1a, B, nullptr);
    gemm_mfma<256, true><<<GEMM_GRID, 256, 0, stream>>>(B, WtH + o2a, WtL + o2a, b2a, B, stats);
    bn_finalize<<<1, 256, 0, stream>>>(stats, ga, ba, scsh);

    // ---- layer 2 (BN1 folded into aggregate) ----
    aggregate_k<256, true><<<AGG_GRID, 256, 0, stream>>>(B, rowptr, col, scsh, A);
    gemm_mfma<256, false><<<GEMM_GRID, 256, 0, stream>>>(A, WtH + o1s0, WtL + o1s0, b1s, A, nullptr);
    gemm_mfma<256, true><<<GEMM_GRID, 256, 0, stream>>>(A, WtH + o2s0, WtL + o2s0, b2s, A, stats + 512);
    bn_finalize<<<1, 256, 0, stream>>>(stats + 512, gs, bs, scsh + 512);

    // ---- layer 3 (BN2 folded into aggregate) ----
    aggregate_k<256, true><<<AGG_GRID, 256, 0, stream>>>(A, rowptr, col, scsh + 512, B);
    gemm_mfma<256, false><<<GEMM_GRID, 256, 0, stream>>>(B, WtH + o1s1, WtL + o1s1, b1s + 256, B, nullptr);
    gemm_mfma<256, true><<<GEMM_GRID, 256, 0, stream>>>(B, WtH + o2s1, WtL + o2s1, b2s + 256, B, stats + 1024);
    bn_finalize<<<1, 256, 0, stream>>>(stats + 1024, gs + 256, bs + 256, scsh + 1024);

    // ---- pool (BN3 folded in) ----
    pool_k<<<N_GRAPHS, 256, 0, stream>>>(B, batch, scsh + 1024, out);
}